// Round 1
// baseline (3271.931 us; speedup 1.0000x reference)
//
#include <hip/hip_runtime.h>
#include <hip/hip_bf16.h>
#include <math.h>

#define N_NODES   100000
#define F_IN      1433
#define H_DIM     16
#define C_DIM     7
#define NGRAPHS   64
#define GPOOL     (NGRAPHS * C_DIM)   // 448

// ---------- helpers ----------
__device__ __forceinline__ unsigned float_key(float f) {
    unsigned b = __float_as_uint(f);
    return (b & 0x80000000u) ? ~b : (b | 0x80000000u);
}
__device__ __forceinline__ float key_float(unsigned u) {
    unsigned b = (u & 0x80000000u) ? (u ^ 0x80000000u) : ~u;
    return __uint_as_float(b);
}

// ---------- degree count (in-degree via dst), deg buffer pre-zeroed ----------
__global__ void k_deg(const int* __restrict__ dst, float* __restrict__ deg, int E) {
    int i = blockIdx.x * 256 + threadIdx.x;
    if (i < E) atomicAdd(&deg[dst[i]], 1.0f);
}

// deg -> inv_sqrt(deg + 1) in place (self-loop adds 1, deg>=1 guaranteed)
__global__ void k_inv(float* __restrict__ deg, int n) {
    int i = blockIdx.x * 256 + threadIdx.x;
    if (i < n) deg[i] = rsqrtf(deg[i] + 1.0f);
}

// ---------- GEMM1: hs1[i][:] = (x[i,:] @ W1) * inv[i]; agg1 seeded with self-loop ----------
// 256 rows/block, K-chunks of 32. Thread tile 4 rows x 4 cols (rg=tid>>2, cg=tid&3).
__global__ __launch_bounds__(256) void k_gemm1(const float* __restrict__ x,
                                               const float* __restrict__ W1,
                                               const float* __restrict__ inv,
                                               float* __restrict__ hs1,
                                               float* __restrict__ agg1) {
    __shared__ float xT[32 * 258];   // [c][r], stride 258 -> 2-way (free) bank pattern
    __shared__ float wt[32 * 16];    // [f][j]
    const int tid = threadIdx.x;
    const int r0  = blockIdx.x * 256;
    const int rg  = tid >> 2;        // 0..63 -> rows rg*4..rg*4+3
    const int cg  = tid & 3;         // 0..3  -> cols cg*4..cg*4+3
    float acc[4][4] = {};

    for (int f0 = 0; f0 < F_IN; f0 += 32) {
        // stage x chunk (coalesced 128B segments), transposed into LDS
        #pragma unroll
        for (int it = 0; it < 32; ++it) {
            int lin = it * 256 + tid;
            int r = lin >> 5, c = lin & 31;
            int row = r0 + r, f = f0 + c;
            float v = 0.0f;
            if (row < N_NODES && f < F_IN) v = x[(size_t)row * F_IN + f];
            xT[c * 258 + r] = v;
        }
        // stage W1 chunk
        #pragma unroll
        for (int it = 0; it < 2; ++it) {
            int lin = it * 256 + tid;
            int f = f0 + (lin >> 4);
            wt[lin] = (f < F_IN) ? W1[f * 16 + (lin & 15)] : 0.0f;
        }
        __syncthreads();

        #pragma unroll
        for (int ff = 0; ff < 32; ++ff) {
            const float2* xf2 = (const float2*)&xT[ff * 258];
            float2 a01 = xf2[rg * 2];
            float2 a23 = xf2[rg * 2 + 1];
            float4 wv  = *(const float4*)&wt[ff * 16 + cg * 4];
            float xa[4] = {a01.x, a01.y, a23.x, a23.y};
            #pragma unroll
            for (int i2 = 0; i2 < 4; ++i2) {
                acc[i2][0] = fmaf(xa[i2], wv.x, acc[i2][0]);
                acc[i2][1] = fmaf(xa[i2], wv.y, acc[i2][1]);
                acc[i2][2] = fmaf(xa[i2], wv.z, acc[i2][2]);
                acc[i2][3] = fmaf(xa[i2], wv.w, acc[i2][3]);
            }
        }
        __syncthreads();
    }

    #pragma unroll
    for (int i2 = 0; i2 < 4; ++i2) {
        int row = r0 + rg * 4 + i2;
        if (row < N_NODES) {
            float s = inv[row];
            float4 v;
            v.x = acc[i2][0] * s; v.y = acc[i2][1] * s;
            v.z = acc[i2][2] * s; v.w = acc[i2][3] * s;
            *(float4*)&hs1[(size_t)row * 16 + cg * 4] = v;   // pre-scaled features
            *(float4*)&agg1[(size_t)row * 16 + cg * 4] = v;  // self-loop seed
        }
    }
}

// ---------- edge scatter layer1: agg1[d] += hs1[s]  (4 threads per edge) ----------
__global__ void k_scatter1(const int* __restrict__ ei, const float* __restrict__ hs1,
                           float* __restrict__ agg1, int E) {
    int t = blockIdx.x * 256 + threadIdx.x;
    int e = t >> 2, cg = t & 3;
    if (e >= E) return;
    int s = ei[e], d = ei[E + e];
    float4 v = *(const float4*)&hs1[(size_t)s * 16 + cg * 4];
    float* p = &agg1[(size_t)d * 16 + cg * 4];
    atomicAdd(p + 0, v.x);
    atomicAdd(p + 1, v.y);
    atomicAdd(p + 2, v.z);
    atomicAdd(p + 3, v.w);
}

// ---------- node layer2: h1 = relu(agg1*inv + b1); hs2 = (h1@W2)*inv; agg2 seeded ----------
__global__ __launch_bounds__(256) void k_node2(const float* __restrict__ agg1,
                                               const float* __restrict__ inv,
                                               const float* __restrict__ b1,
                                               const float* __restrict__ W2,
                                               float* __restrict__ hs2,
                                               float* __restrict__ agg2, int n) {
    __shared__ float sW[16 * 7];
    __shared__ float sb1[16];
    if (threadIdx.x < 112) sW[threadIdx.x] = W2[threadIdx.x];
    if (threadIdx.x < 16) sb1[threadIdx.x] = b1[threadIdx.x];
    __syncthreads();
    int i = blockIdx.x * 256 + threadIdx.x;
    if (i >= n) return;
    float s = inv[i];
    float h[16];
    #pragma unroll
    for (int j = 0; j < 16; j += 4) {
        float4 a = *(const float4*)&agg1[(size_t)i * 16 + j];
        h[j + 0] = fmaxf(fmaf(a.x, s, sb1[j + 0]), 0.0f);
        h[j + 1] = fmaxf(fmaf(a.y, s, sb1[j + 1]), 0.0f);
        h[j + 2] = fmaxf(fmaf(a.z, s, sb1[j + 2]), 0.0f);
        h[j + 3] = fmaxf(fmaf(a.w, s, sb1[j + 3]), 0.0f);
    }
    float o[7] = {};
    #pragma unroll
    for (int j = 0; j < 16; ++j) {
        #pragma unroll
        for (int k = 0; k < 7; ++k) o[k] = fmaf(h[j], sW[j * 7 + k], o[k]);
    }
    #pragma unroll
    for (int k = 0; k < 7; ++k) {
        float v = o[k] * s;
        hs2[(size_t)i * 7 + k] = v;
        agg2[(size_t)i * 7 + k] = v;
    }
}

// ---------- edge scatter layer2: agg2[d] += hs2[s] ----------
__global__ void k_scatter2(const int* __restrict__ ei, const float* __restrict__ hs2,
                           float* __restrict__ agg2, int E) {
    int e = blockIdx.x * 256 + threadIdx.x;
    if (e >= E) return;
    int s = ei[e], d = ei[E + e];
    #pragma unroll
    for (int k = 0; k < 7; ++k)
        atomicAdd(&agg2[(size_t)d * 7 + k], hs2[(size_t)s * 7 + k]);
}

// ---------- finalize: z = agg2*inv + b2; log_softmax -> out; segmented max-pool ----------
__global__ __launch_bounds__(256) void k_final(const float* __restrict__ agg2,
                                               const float* __restrict__ inv,
                                               const float* __restrict__ b2,
                                               const int* __restrict__ batch,
                                               float* __restrict__ out,
                                               unsigned* __restrict__ gkeys, int n) {
    __shared__ unsigned lmax[GPOOL];
    for (int t = threadIdx.x; t < GPOOL; t += 256) lmax[t] = 0u;
    __syncthreads();
    int i = blockIdx.x * 256 + threadIdx.x;
    if (i < n) {
        float s = inv[i];
        float z[7];
        #pragma unroll
        for (int k = 0; k < 7; ++k) z[k] = fmaf(agg2[(size_t)i * 7 + k], s, b2[k]);
        float m = z[0];
        #pragma unroll
        for (int k = 1; k < 7; ++k) m = fmaxf(m, z[k]);
        float sum = 0.0f;
        #pragma unroll
        for (int k = 0; k < 7; ++k) sum += expf(z[k] - m);
        float l = logf(sum);
        #pragma unroll
        for (int k = 0; k < 7; ++k) out[GPOOL + (size_t)i * 7 + k] = z[k] - m - l;
        int b = batch[i];
        #pragma unroll
        for (int k = 0; k < 7; ++k) atomicMax(&lmax[b * 7 + k], float_key(z[k]));
    }
    __syncthreads();
    for (int t = threadIdx.x; t < GPOOL; t += 256) {
        unsigned v = lmax[t];
        if (v) atomicMax(&gkeys[t], v);
    }
}

__global__ void k_decode(const unsigned* __restrict__ gkeys, float* __restrict__ out) {
    int t = blockIdx.x * 64 + threadIdx.x;
    if (t < GPOOL) out[t] = key_float(gkeys[t]);
}

extern "C" void kernel_launch(void* const* d_in, const int* in_sizes, int n_in,
                              void* d_out, int out_size, void* d_ws, size_t ws_size,
                              hipStream_t stream) {
    const float* x    = (const float*)d_in[0];
    const int*   ei   = (const int*)d_in[1];
    const int*   batch= (const int*)d_in[2];
    const float* W1   = (const float*)d_in[3];
    const float* b1   = (const float*)d_in[4];
    const float* W2   = (const float*)d_in[5];
    const float* b2   = (const float*)d_in[6];
    float* out = (float*)d_out;
    const int E = in_sizes[1] / 2;
    const int n = in_sizes[0] / F_IN;

    // workspace layout (floats): inv | hs1(16n) | agg1(16n) | hs2(7n) | agg2(7n) | gkeys(448 u32)
    float* ws   = (float*)d_ws;
    float* inv  = ws;
    float* hs1  = inv  + (size_t)n;
    float* agg1 = hs1  + (size_t)n * 16;
    float* hs2  = agg1 + (size_t)n * 16;
    float* agg2 = hs2  + (size_t)n * 7;
    unsigned* gkeys = (unsigned*)(agg2 + (size_t)n * 7);

    hipMemsetAsync(inv, 0, (size_t)n * sizeof(float), stream);
    hipMemsetAsync(gkeys, 0, GPOOL * sizeof(unsigned), stream);

    k_deg<<<(E + 255) / 256, 256, 0, stream>>>(ei + E, inv, E);
    k_inv<<<(n + 255) / 256, 256, 0, stream>>>(inv, n);
    k_gemm1<<<(n + 255) / 256, 256, 0, stream>>>(x, W1, inv, hs1, agg1);
    k_scatter1<<<((size_t)E * 4 + 255) / 256, 256, 0, stream>>>(ei, hs1, agg1, E);
    k_node2<<<(n + 255) / 256, 256, 0, stream>>>(agg1, inv, b1, W2, hs2, agg2, n);
    k_scatter2<<<(E + 255) / 256, 256, 0, stream>>>(ei, hs2, agg2, E);
    k_final<<<(n + 255) / 256, 256, 0, stream>>>(agg2, inv, b2, batch, out, gkeys, n);
    k_decode<<<7, 64, 0, stream>>>(gkeys, out);
}

// Round 2
// 1891.844 us; speedup vs baseline: 1.7295x; 1.7295x over previous
//
#include <hip/hip_runtime.h>
#include <hip/hip_bf16.h>
#include <math.h>

#define N_NODES   100000
#define F_IN      1433
#define H_DIM     16
#define C_DIM     7
#define NGRAPHS   64
#define GPOOL     (NGRAPHS * C_DIM)   // 448
#define SCAN_CHUNK 1024

// ---------- helpers ----------
__device__ __forceinline__ unsigned float_key(float f) {
    unsigned b = __float_as_uint(f);
    return (b & 0x80000000u) ? ~b : (b | 0x80000000u);
}
__device__ __forceinline__ float key_float(unsigned u) {
    unsigned b = (u & 0x80000000u) ? (u ^ 0x80000000u) : ~u;
    return __uint_as_float(b);
}

// ---------- in-degree count (int atomics), deg pre-zeroed ----------
__global__ void k_deg(const int* __restrict__ dst, int* __restrict__ deg, int E) {
    int i = blockIdx.x * 256 + threadIdx.x;
    if (i < E) atomicAdd(&deg[dst[i]], 1);
}

// ---------- exclusive scan of deg -> cursor (3 kernels) ----------
__global__ void k_scan_block(const int* __restrict__ deg, int* __restrict__ cursor,
                             int* __restrict__ bsum, int n) {
    __shared__ int sh[256];
    int base = blockIdx.x * SCAN_CHUNK + threadIdx.x * 4;
    int v[4]; int sum = 0;
    #pragma unroll
    for (int j = 0; j < 4; ++j) { int idx = base + j; v[j] = (idx < n) ? deg[idx] : 0; sum += v[j]; }
    sh[threadIdx.x] = sum;
    __syncthreads();
    for (int off = 1; off < 256; off <<= 1) {
        int t = (threadIdx.x >= off) ? sh[threadIdx.x - off] : 0;
        __syncthreads();
        sh[threadIdx.x] += t;
        __syncthreads();
    }
    int excl = (threadIdx.x > 0) ? sh[threadIdx.x - 1] : 0;
    if (threadIdx.x == 255) bsum[blockIdx.x] = sh[255];
    int run = excl;
    #pragma unroll
    for (int j = 0; j < 4; ++j) { int idx = base + j; if (idx < n) cursor[idx] = run; run += v[j]; }
}

__global__ void k_scan_top(int* __restrict__ bsum, int nb) {
    __shared__ int sh[128];
    int v = (threadIdx.x < nb) ? bsum[threadIdx.x] : 0;
    sh[threadIdx.x] = v;
    __syncthreads();
    for (int off = 1; off < 128; off <<= 1) {
        int t = (threadIdx.x >= off) ? sh[threadIdx.x - off] : 0;
        __syncthreads();
        sh[threadIdx.x] += t;
        __syncthreads();
    }
    if (threadIdx.x < nb) bsum[threadIdx.x] = (threadIdx.x > 0) ? sh[threadIdx.x - 1] : 0;
}

__global__ void k_scan_add(int* __restrict__ cursor, const int* __restrict__ bsum, int n) {
    int i = blockIdx.x * 256 + threadIdx.x;
    if (i < n) cursor[i] += bsum[i >> 10];
}

// ---------- CSR fill: cursor mutates from start-offset to end-offset ----------
__global__ void k_fill(const int* __restrict__ ei, int* __restrict__ cursor,
                       int* __restrict__ csr, int E) {
    int e = blockIdx.x * 256 + threadIdx.x;
    if (e < E) {
        int s = ei[e], d = ei[E + e];
        int pos = atomicAdd(&cursor[d], 1);
        csr[pos] = s;
    }
}

// inv = rsqrt(deg + 1)
__global__ void k_inv(const int* __restrict__ deg, float* __restrict__ inv, int n) {
    int i = blockIdx.x * 256 + threadIdx.x;
    if (i < n) inv[i] = rsqrtf((float)deg[i] + 1.0f);
}

// ---------- GEMM1: hs1[i][:] = (x[i,:] @ W1) * inv[i] ----------
__global__ __launch_bounds__(256) void k_gemm1(const float* __restrict__ x,
                                               const float* __restrict__ W1,
                                               const float* __restrict__ inv,
                                               float* __restrict__ hs1) {
    __shared__ float xT[32 * 258];
    __shared__ float wt[32 * 16];
    const int tid = threadIdx.x;
    const int r0  = blockIdx.x * 256;
    const int rg  = tid >> 2;
    const int cg  = tid & 3;
    float acc[4][4] = {};

    for (int f0 = 0; f0 < F_IN; f0 += 32) {
        #pragma unroll
        for (int it = 0; it < 32; ++it) {
            int lin = it * 256 + tid;
            int r = lin >> 5, c = lin & 31;
            int row = r0 + r, f = f0 + c;
            float v = 0.0f;
            if (row < N_NODES && f < F_IN) v = x[(size_t)row * F_IN + f];
            xT[c * 258 + r] = v;
        }
        #pragma unroll
        for (int it = 0; it < 2; ++it) {
            int lin = it * 256 + tid;
            int f = f0 + (lin >> 4);
            wt[lin] = (f < F_IN) ? W1[f * 16 + (lin & 15)] : 0.0f;
        }
        __syncthreads();

        #pragma unroll
        for (int ff = 0; ff < 32; ++ff) {
            const float2* xf2 = (const float2*)&xT[ff * 258];
            float2 a01 = xf2[rg * 2];
            float2 a23 = xf2[rg * 2 + 1];
            float4 wv  = *(const float4*)&wt[ff * 16 + cg * 4];
            float xa[4] = {a01.x, a01.y, a23.x, a23.y};
            #pragma unroll
            for (int i2 = 0; i2 < 4; ++i2) {
                acc[i2][0] = fmaf(xa[i2], wv.x, acc[i2][0]);
                acc[i2][1] = fmaf(xa[i2], wv.y, acc[i2][1]);
                acc[i2][2] = fmaf(xa[i2], wv.z, acc[i2][2]);
                acc[i2][3] = fmaf(xa[i2], wv.w, acc[i2][3]);
            }
        }
        __syncthreads();
    }

    #pragma unroll
    for (int i2 = 0; i2 < 4; ++i2) {
        int row = r0 + rg * 4 + i2;
        if (row < N_NODES) {
            float s = inv[row];
            float4 v;
            v.x = acc[i2][0] * s; v.y = acc[i2][1] * s;
            v.z = acc[i2][2] * s; v.w = acc[i2][3] * s;
            *(float4*)&hs1[(size_t)row * 16 + cg * 4] = v;
        }
    }
}

// ---------- layer1 gather + relu + layer2 linear: hs2 = relu(agg1*inv+b1) @ W2 * inv ----------
// cursor[i] now holds END offset; start = end - deg[i]. 16 nodes/block, 16 threads/node.
__global__ __launch_bounds__(256) void k_agg1(const float* __restrict__ hs1,
                                              const int* __restrict__ cursor,
                                              const int* __restrict__ deg,
                                              const int* __restrict__ csr,
                                              const float* __restrict__ inv,
                                              const float* __restrict__ b1,
                                              const float* __restrict__ W2,
                                              float* __restrict__ hs2, int n) {
    __shared__ float sh[16][17];
    __shared__ float sW[112];
    __shared__ float sb[16];
    if (threadIdx.x < 112) sW[threadIdx.x] = W2[threadIdx.x];
    if (threadIdx.x < 16)  sb[threadIdx.x] = b1[threadIdx.x];
    __syncthreads();
    const int nl = threadIdx.x >> 4, f = threadIdx.x & 15;
    const int i = blockIdx.x * 16 + nl;
    float h = 0.0f;
    if (i < n) {
        float acc = hs1[(size_t)i * 16 + f];       // self-loop (pre-scaled)
        int en = cursor[i], st = en - deg[i];
        for (int j = st; j < en; ++j) {
            int s2 = csr[j];
            acc += hs1[(size_t)s2 * 16 + f];
        }
        h = fmaxf(fmaf(acc, inv[i], sb[f]), 0.0f);
    }
    sh[nl][f] = h;
    __syncthreads();
    if (threadIdx.x < 112) {
        int nl2 = threadIdx.x / 7, k = threadIdx.x % 7;
        int i2 = blockIdx.x * 16 + nl2;
        if (i2 < n) {
            float o = 0.0f;
            #pragma unroll
            for (int j = 0; j < 16; ++j) o = fmaf(sh[nl2][j], sW[j * 7 + k], o);
            hs2[(size_t)i2 * 7 + k] = o * inv[i2];
        }
    }
}

// ---------- layer2 gather + bias + log_softmax + graph max-pool ----------
// 32 nodes/block, 8 threads/node (7 active).
__global__ __launch_bounds__(256) void k_agg2(const float* __restrict__ hs2,
                                              const int* __restrict__ cursor,
                                              const int* __restrict__ deg,
                                              const int* __restrict__ csr,
                                              const float* __restrict__ inv,
                                              const float* __restrict__ b2,
                                              const int* __restrict__ batch,
                                              float* __restrict__ out,
                                              unsigned* __restrict__ gkeys, int n) {
    __shared__ unsigned lmax[GPOOL];
    for (int t = threadIdx.x; t < GPOOL; t += 256) lmax[t] = 0u;
    __syncthreads();
    const int nl = threadIdx.x >> 3, k = threadIdx.x & 7;
    const int i = blockIdx.x * 32 + nl;
    if (i < n) {
        float z = -INFINITY;
        if (k < 7) {
            float acc = hs2[(size_t)i * 7 + k];    // self-loop (pre-scaled)
            int en = cursor[i], st = en - deg[i];
            for (int j = st; j < en; ++j) {
                int s2 = csr[j];
                acc += hs2[(size_t)s2 * 7 + k];
            }
            z = fmaf(acc, inv[i], b2[k]);
        }
        float m = z;
        #pragma unroll
        for (int off = 4; off >= 1; off >>= 1) m = fmaxf(m, __shfl_xor(m, off, 8));
        float e = (k < 7) ? expf(z - m) : 0.0f;
        float ssum = e;
        #pragma unroll
        for (int off = 4; off >= 1; off >>= 1) ssum += __shfl_xor(ssum, off, 8);
        float l = logf(ssum);
        if (k < 7) {
            out[GPOOL + (size_t)i * 7 + k] = z - m - l;
            int b = batch[i];
            atomicMax(&lmax[b * 7 + k], float_key(z));
        }
    }
    __syncthreads();
    for (int t = threadIdx.x; t < GPOOL; t += 256) {
        unsigned v = lmax[t];
        if (v) atomicMax(&gkeys[t], v);
    }
}

__global__ void k_decode(const unsigned* __restrict__ gkeys, float* __restrict__ out) {
    int t = blockIdx.x * 64 + threadIdx.x;
    if (t < GPOOL) out[t] = key_float(gkeys[t]);
}

extern "C" void kernel_launch(void* const* d_in, const int* in_sizes, int n_in,
                              void* d_out, int out_size, void* d_ws, size_t ws_size,
                              hipStream_t stream) {
    const float* x    = (const float*)d_in[0];
    const int*   ei   = (const int*)d_in[1];
    const int*   batch= (const int*)d_in[2];
    const float* W1   = (const float*)d_in[3];
    const float* b1   = (const float*)d_in[4];
    const float* W2   = (const float*)d_in[5];
    const float* b2   = (const float*)d_in[6];
    float* out = (float*)d_out;
    const int E = in_sizes[1] / 2;
    const int n = in_sizes[0] / F_IN;
    const int nb = (n + SCAN_CHUNK - 1) / SCAN_CHUNK;   // 98

    // workspace: deg(int n) | cursor(int n) | bsum(int 128) | csr(int E) |
    //            inv(f n) | hs1(f 16n) | hs2(f 7n) | gkeys(u32 448)
    int* deg    = (int*)d_ws;
    int* cursor = deg + n;
    int* bsum   = cursor + n;
    int* csr    = bsum + 128;
    float* inv  = (float*)(csr + E);
    float* hs1  = inv + n;
    float* hs2  = hs1 + (size_t)n * 16;
    unsigned* gkeys = (unsigned*)(hs2 + (size_t)n * 7);

    hipMemsetAsync(deg, 0, (size_t)n * sizeof(int), stream);
    hipMemsetAsync(gkeys, 0, GPOOL * sizeof(unsigned), stream);

    k_deg<<<(E + 255) / 256, 256, 0, stream>>>(ei + E, deg, E);
    k_scan_block<<<nb, 256, 0, stream>>>(deg, cursor, bsum, n);
    k_scan_top<<<1, 128, 0, stream>>>(bsum, nb);
    k_scan_add<<<(n + 255) / 256, 256, 0, stream>>>(cursor, bsum, n);
    k_fill<<<(E + 255) / 256, 256, 0, stream>>>(ei, cursor, csr, E);
    k_inv<<<(n + 255) / 256, 256, 0, stream>>>(deg, inv, n);
    k_gemm1<<<(n + 255) / 256, 256, 0, stream>>>(x, W1, inv, hs1);
    k_agg1<<<(n + 15) / 16, 256, 0, stream>>>(hs1, cursor, deg, csr, inv, b1, W2, hs2, n);
    k_agg2<<<(n + 31) / 32, 256, 0, stream>>>(hs2, cursor, deg, csr, inv, b2, batch, out, gkeys, n);
    k_decode<<<7, 64, 0, stream>>>(gkeys, out);
}